// Round 1
// baseline (25142.867 us; speedup 1.0000x reference)
//
#include <hip/hip_runtime.h>

#define V  32000
#define E  256
#define H  512
#define BB 32
#define TS 512
#define TT 128
#define NT 127   // decoder steps = TT-1

// ---- workspace layout (float words) ----
#define OFF_WBF  0ull            // ushort[512*32000] -> 8,192,000 float words
#define OFF_WT   8192000ull      // float[32000*512]  (Wout^T)
#define OFF_PT   24576000ull     // top2 partials: 250*32*2*(val,idx) = 32000 words
#define OFF_H0   24608000ull     // 2 * 32*512 ping-pong
#define OFF_H1   24640768ull
#define OFF_TOK  24673536ull     // 32 ints
#define OFF_CNT  24673568ull     // 1 int
// total ~24.67M words = 98.7 MB.  pre0 (512*32*512 f32 = 33.5MB) lives in d_out
// (consumed entirely before the decoder starts writing logits there).

__device__ inline unsigned short f2bf(float f){
  unsigned int x = __float_as_uint(f);
  unsigned int r = x + 0x7fffu + ((x >> 16) & 1u);
  return (unsigned short)(r >> 16);
}
__device__ inline float bf2f(unsigned short u){
  return __uint_as_float(((unsigned int)u) << 16);
}

// merge candidate (o1,oi1,o2,oi2) into running top-2 (v1,i1,v2,i2); ties -> lower idx
__device__ inline void top2_merge(float& v1,int& i1,float& v2,int& i2,
                                  float o1,int oi1,float o2,int oi2){
  if (o1 > v1 || (o1 == v1 && oi1 < i1)) {
    float nv2; int ni2;
    if (v1 > o2 || (v1 == o2 && i1 < oi2)) { nv2 = v1; ni2 = i1; }
    else { nv2 = o2; ni2 = oi2; }
    v1 = o1; i1 = oi1; v2 = nv2; i2 = ni2;
  } else if (o1 > v2 || (o1 == v2 && oi1 < i2)) {
    v2 = o1; i2 = oi1;
  }
}

// ---------------- init: zero hidden ping-pongs, seed tokens, zero counter ----
__global__ void k_init(float* ws, const int* tgt){
  int gid = blockIdx.x*256 + threadIdx.x;
  float* h0 = ws + OFF_H0; float* h1 = ws + OFF_H1;
  if (gid < 2*BB*H){ h0[gid] = 0.f; h1[gid] = 0.f; }
  if (gid < BB) ((int*)(ws+OFF_TOK))[gid] = tgt[gid*TT + 0];
  if (gid == 0) ((int*)(ws+OFF_CNT))[0] = 0;
}

// ------------- Wout prep: bf16 copy ([k][v]) + fp32 transpose ([v][k]) -------
__global__ void k_wprep(float* ws, const float* wout){
  int tw = blockIdx.x; int k0 = (tw / 500) * 64; int v0 = (tw % 500) * 64;
  __shared__ float tile[64][65];
  unsigned short* wbf = (unsigned short*)(ws + OFF_WBF);
  float* wt = ws + OFF_WT;
  for (int i = threadIdx.x; i < 64*64; i += 256){
    int kk = i >> 6, vv = i & 63;
    float val = wout[(size_t)(k0+kk)*V + v0 + vv];
    tile[kk][vv] = val;
    wbf[(size_t)(k0+kk)*V + v0 + vv] = f2bf(val);
  }
  __syncthreads();
  for (int i = threadIdx.x; i < 64*64; i += 256){
    int vv = i >> 6, kk = i & 63;
    wt[(size_t)(v0+vv)*H + k0 + kk] = tile[kk][vv];
  }
}

// ------------- pre0[t][b][j] = b0[j] + emb_enc[src[b][t]] @ Wih0 -------------
__global__ void k_pre0(float* pre0, const int* src, const float* emb,
                       const float* Wih0, const float* b0){
  int t = blockIdx.x >> 2; int cb = blockIdx.x & 3;
  __shared__ int sidx[32];
  __shared__ float sA[32][257];
  int tid = threadIdx.x;
  if (tid < 32) sidx[tid] = src[tid*TS + t];
  __syncthreads();
  for (int i = tid; i < 32*E; i += 256){
    int bb = i >> 8, e = i & 255;
    sA[bb][e] = emb[(size_t)sidx[bb]*E + e];
  }
  __syncthreads();
  int c = tid & 127, rh = tid >> 7;
  int j = cb*128 + c;
  float bj = b0[j];
  float acc[16];
  #pragma unroll
  for (int i=0;i<16;i++) acc[i] = bj;
  for (int k=0;k<E;k++){
    float w = Wih0[(size_t)k*H + j];
    #pragma unroll
    for (int i=0;i<16;i++) acc[i] += sA[rh*16+i][k]*w;
  }
  #pragma unroll
  for (int i=0;i<16;i++){
    int b = rh*16 + i;
    pre0[((size_t)t*BB + b)*H + j] = acc[i];
  }
}

// ------------- encoder step tau: layer0 computes h0_tau, layer1 computes h1_{tau-1}
__global__ void k_enc(float* ws, const float* pre0, const float* Whh0,
                      const float* Wih1, const float* Whh1, const float* b1, int tau){
  float* h0 = ws + OFF_H0; float* h1 = ws + OFF_H1;
  int wg = blockIdx.x; int tid = threadIdx.x;
  if (wg < 64){
    if (tau >= TS) return;
    int rb = wg >> 3, cb = wg & 7;
    __shared__ float sh[4][513];
    const float* hprev = h0 + ((tau+1)&1)*BB*H;
    for (int i=tid;i<4*H;i+=256){ int rr=i>>9, k=i&511; sh[rr][k]=hprev[(rb*4+rr)*H+k]; }
    __syncthreads();
    int c = tid & 63, rsub = tid >> 6;
    int r = rb*4 + rsub, j = cb*64 + c;
    const float* w = Whh0 + j;
    float a0=0,a1=0,a2=0,a3=0;
    for (int k=0;k<H;k+=4){
      a0 += sh[rsub][k+0]*w[(size_t)(k+0)*H];
      a1 += sh[rsub][k+1]*w[(size_t)(k+1)*H];
      a2 += sh[rsub][k+2]*w[(size_t)(k+2)*H];
      a3 += sh[rsub][k+3]*w[(size_t)(k+3)*H];
    }
    float acc = pre0[((size_t)tau*BB + r)*H + j] + ((a0+a1)+(a2+a3));
    h0[(tau&1)*BB*H + r*H + j] = tanhf(acc);
  } else {
    if (tau < 1) return;
    int w2 = wg - 64;
    int rb = w2 >> 4, cb = w2 & 15;
    __shared__ float s0[4][513];
    __shared__ float s1[4][513];
    __shared__ float sp[256];
    const float* h0t = h0 + ((tau+1)&1)*BB*H;  // h0_{tau-1}
    const float* h1p = h1 + (tau&1)*BB*H;      // h1_{tau-2}
    for (int i=tid;i<4*H;i+=256){
      int rr=i>>9, k=i&511;
      s0[rr][k] = h0t[(rb*4+rr)*H+k];
      s1[rr][k] = h1p[(rb*4+rr)*H+k];
    }
    __syncthreads();
    int kh = tid >> 7, q = tid & 127;
    int c = q & 31, rsub = q >> 5;
    int r = rb*4 + rsub, j = cb*32 + c;
    const float* W = kh ? (Whh1 + j) : (Wih1 + j);
    float (*sh)[513] = kh ? s1 : s0;
    float a0=0,a1=0,a2=0,a3=0;
    for (int k=0;k<H;k+=4){
      a0 += sh[rsub][k+0]*W[(size_t)(k+0)*H];
      a1 += sh[rsub][k+1]*W[(size_t)(k+1)*H];
      a2 += sh[rsub][k+2]*W[(size_t)(k+2)*H];
      a3 += sh[rsub][k+3]*W[(size_t)(k+3)*H];
    }
    sp[tid] = ((a0+a1)+(a2+a3));
    __syncthreads();
    if (kh == 0){
      float v = sp[q] + sp[128+q] + b1[j];
      h1[((tau+1)&1)*BB*H + r*H + j] = tanhf(v);
    }
  }
}

// ------------- decoder cell layer0: h0 = tanh(emb[tok]@Wih0 + h0@Whh0 + b0) ---
__global__ void k_cellA(float* ws, const float* embd, const float* Wih0,
                        const float* Whh0, const float* b0, int t){
  float* h0 = ws + OFF_H0;
  const int* tok = (const int*)(ws + OFF_TOK);
  int rb = blockIdx.x >> 3, cb = blockIdx.x & 7;
  __shared__ int stok[4];
  __shared__ float sx[4][257];
  __shared__ float sh[4][513];
  int tid = threadIdx.x;
  if (tid < 4) stok[tid] = tok[rb*4 + tid];
  __syncthreads();
  for (int i=tid;i<4*E;i+=256){ int rr=i>>8, e=i&255; sx[rr][e] = embd[(size_t)stok[rr]*E + e]; }
  const float* hprev = h0 + ((t+1)&1)*BB*H;
  for (int i=tid;i<4*H;i+=256){ int rr=i>>9, k=i&511; sh[rr][k] = hprev[(rb*4+rr)*H + k]; }
  __syncthreads();
  int c = tid & 63, rsub = tid >> 6;
  int r = rb*4 + rsub, j = cb*64 + c;
  float a0=0,a1=0,a2=0,a3=0;
  for (int k=0;k<E;k+=4){
    a0 += sx[rsub][k+0]*Wih0[(size_t)(k+0)*H + j];
    a1 += sx[rsub][k+1]*Wih0[(size_t)(k+1)*H + j];
    a2 += sx[rsub][k+2]*Wih0[(size_t)(k+2)*H + j];
    a3 += sx[rsub][k+3]*Wih0[(size_t)(k+3)*H + j];
  }
  for (int k=0;k<H;k+=4){
    a0 += sh[rsub][k+0]*Whh0[(size_t)(k+0)*H + j];
    a1 += sh[rsub][k+1]*Whh0[(size_t)(k+1)*H + j];
    a2 += sh[rsub][k+2]*Whh0[(size_t)(k+2)*H + j];
    a3 += sh[rsub][k+3]*Whh0[(size_t)(k+3)*H + j];
  }
  h0[(t&1)*BB*H + r*H + j] = tanhf(b0[j] + ((a0+a1)+(a2+a3)));
}

// ------------- decoder cell layer1: h1 = tanh(h0@Wih1 + h1@Whh1 + b1) --------
__global__ void k_cellB(float* ws, const float* Wih1, const float* Whh1,
                        const float* b1, int t){
  float* h0 = ws + OFF_H0; float* h1 = ws + OFF_H1;
  int rb = blockIdx.x >> 4, cb = blockIdx.x & 15;
  __shared__ float s0[4][513];
  __shared__ float s1[4][513];
  __shared__ float sp[256];
  int tid = threadIdx.x;
  const float* h0c = h0 + (t&1)*BB*H;
  const float* h1p = h1 + ((t+1)&1)*BB*H;
  for (int i=tid;i<4*H;i+=256){
    int rr=i>>9, k=i&511;
    s0[rr][k] = h0c[(rb*4+rr)*H+k];
    s1[rr][k] = h1p[(rb*4+rr)*H+k];
  }
  __syncthreads();
  int kh = tid >> 7, q = tid & 127;
  int c = q & 31, rsub = q >> 5;
  int r = rb*4 + rsub, j = cb*32 + c;
  const float* W = kh ? (Whh1 + j) : (Wih1 + j);
  float (*sh)[513] = kh ? s1 : s0;
  float a0=0,a1=0,a2=0,a3=0;
  for (int k=0;k<H;k+=4){
    a0 += sh[rsub][k+0]*W[(size_t)(k+0)*H];
    a1 += sh[rsub][k+1]*W[(size_t)(k+1)*H];
    a2 += sh[rsub][k+2]*W[(size_t)(k+2)*H];
    a3 += sh[rsub][k+3]*W[(size_t)(k+3)*H];
  }
  sp[tid] = ((a0+a1)+(a2+a3));
  __syncthreads();
  if (kh == 0){
    float v = sp[q] + sp[128+q] + b1[j];
    h1[(t&1)*BB*H + r*H + j] = tanhf(v);
  }
}

// ------------- logits (bf16 weights) + top2 partials + last-WG argmax/select --
__global__ void k_logits(float* ws, float* out, const float* bout,
                         const int* tgt, const int* tf, int t){
  float* h1 = ws + OFF_H1;
  const unsigned short* wbf = (const unsigned short*)(ws + OFF_WBF);
  const float* wt = ws + OFF_WT;
  float* pt = ws + OFF_PT;
  int* tok = (int*)(ws + OFF_TOK);
  int* cnt = (int*)(ws + OFF_CNT);
  int wg = blockIdx.x; int tid = threadIdx.x;
  int rb = wg / 250, cb = wg % 250;
  __shared__ float Lh[16][513];
  const float* h1c = h1 + (t&1)*BB*H;
  for (int i=tid;i<16*H;i+=256){ int rr=i>>9, k=i&511; Lh[rr][k] = h1c[(rb*16+rr)*H + k]; }
  __syncthreads();
  int c = tid & 127, rh = tid >> 7;
  int j = cb*128 + c;
  float bj = bout[j];
  float acc[8];
  #pragma unroll
  for (int i=0;i<8;i++) acc[i] = bj;
  for (int k=0;k<H;k++){
    float w = bf2f(wbf[(size_t)k*V + j]);
    #pragma unroll
    for (int i=0;i<8;i++) acc[i] += Lh[rh*8+i][k]*w;
  }
  #pragma unroll
  for (int i=0;i<8;i++){
    int b = rb*16 + rh*8 + i;
    out[((size_t)b*NT + t)*V + j] = acc[i];
  }
  // per-(row, colblock) top-2
  __shared__ float sv[16][129];
  __shared__ int   si_[16][129];
  #pragma unroll
  for (int i=0;i<8;i++){ sv[rh*8+i][c] = acc[i]; si_[rh*8+i][c] = j; }
  __syncthreads();
  int row = tid >> 4, l16 = tid & 15;
  float v1=-1e30f, v2=-1e30f; int i1=-1, i2=-1;
  for (int s=0;s<8;s++){
    float v = sv[row][l16 + 16*s]; int ix = si_[row][l16 + 16*s];
    top2_merge(v1,i1,v2,i2, v,ix,-1e30f,-1);
  }
  for (int off=8; off>=1; off>>=1){
    float o1 = __shfl_xor(v1, off, 16); int oi1 = __shfl_xor(i1, off, 16);
    float o2 = __shfl_xor(v2, off, 16); int oi2 = __shfl_xor(i2, off, 16);
    top2_merge(v1,i1,v2,i2, o1,oi1,o2,oi2);
  }
  if (l16 == 0){
    int b = rb*16 + row;
    size_t base = ((size_t)cb*32 + b)*4;
    pt[base+0] = v1; ((int*)pt)[base+1] = i1;
    pt[base+2] = v2; ((int*)pt)[base+3] = i2;
  }
  __threadfence();
  __syncthreads();
  __shared__ int lastflag;
  if (tid == 0){
    int old = atomicAdd(cnt, 1);
    lastflag = (old == (int)gridDim.x - 1);
  }
  __syncthreads();
  if (!lastflag) return;
  __threadfence();
  // ---- select phase (one WG): global max, candidates within delta, fp32 refine
  int b = tid >> 3, l = tid & 7;
  float gm = -1e30f;
  for (int cc=l; cc<250; cc+=8) gm = fmaxf(gm, pt[((size_t)cc*32 + b)*4]);
  for (int off=4; off>=1; off>>=1) gm = fmaxf(gm, __shfl_xor(gm, off, 8));
  __shared__ int candn[32];
  __shared__ int candj[32][6];
  if (l == 0) candn[b] = 0;
  __syncthreads();
  float thr = gm - 0.02f;
  for (int cc=l; cc<250; cc+=8){
    #pragma unroll
    for (int s=0;s<2;s++){
      size_t base = ((size_t)cc*32 + b)*4 + s*2;
      float v = pt[base];
      if (v >= thr){
        int slot = atomicAdd(&candn[b], 1);
        if (slot < 6) candj[b][slot] = ((int*)pt)[base+1];
      }
    }
  }
  __syncthreads();
  int n = candn[b]; if (n > 6) n = 6;
  int besti;
  if (n == 1){
    besti = candj[b][0];
  } else {
    float bestv = -1e30f; besti = 0x7fffffff;
    for (int s=0;s<n;s++){
      int jj = candj[b][s];
      const float* wr = wt + (size_t)jj*H;
      const float* hr = h1c + b*H;
      float p = 0.f;
      for (int kk=l*64; kk<l*64+64; kk++) p += hr[kk]*wr[kk];
      for (int off=4; off>=1; off>>=1) p += __shfl_xor(p, off, 8);
      p += bout[jj];
      if (p > bestv || (p == bestv && jj < besti)){ bestv = p; besti = jj; }
    }
  }
  if (l == 0) tok[b] = (tf[t] > 0) ? tgt[b*TT + t + 1] : besti;
  if (tid == 0) *cnt = 0;
}

extern "C" void kernel_launch(void* const* d_in, const int* in_sizes, int n_in,
                              void* d_out, int out_size, void* d_ws, size_t ws_size,
                              hipStream_t stream) {
  (void)in_sizes; (void)n_in; (void)out_size; (void)ws_size;
  const int*   src     = (const int*)  d_in[0];
  const int*   tgt     = (const int*)  d_in[1];
  const int*   tf      = (const int*)  d_in[2];
  const float* emb_enc = (const float*)d_in[3];
  const float* emb_dec = (const float*)d_in[4];
  const float* eW0     = (const float*)d_in[5];
  const float* eU0     = (const float*)d_in[6];
  const float* eb0     = (const float*)d_in[7];
  const float* eW1     = (const float*)d_in[8];
  const float* eU1     = (const float*)d_in[9];
  const float* eb1     = (const float*)d_in[10];
  const float* dW0     = (const float*)d_in[11];
  const float* dU0     = (const float*)d_in[12];
  const float* db0     = (const float*)d_in[13];
  const float* dW1     = (const float*)d_in[14];
  const float* dU1     = (const float*)d_in[15];
  const float* db1     = (const float*)d_in[16];
  const float* Wout    = (const float*)d_in[17];
  const float* bout    = (const float*)d_in[18];
  float* out = (float*)d_out;
  float* ws  = (float*)d_ws;
  float* pre0 = out;  // scratch alias: fully consumed before decoder writes logits

  k_init <<<128, 256, 0, stream>>>(ws, tgt);
  k_wprep<<<4000,256, 0, stream>>>(ws, Wout);
  k_pre0 <<<2048,256, 0, stream>>>(pre0, src, emb_enc, eW0, eb0);
  for (int tau = 0; tau <= TS; ++tau)
    k_enc<<<192, 256, 0, stream>>>(ws, pre0, eU0, eW1, eU1, eb1, tau);
  for (int t = 0; t < NT; ++t){
    k_cellA <<<64,  256, 0, stream>>>(ws, emb_dec, dW0, dU0, db0, t);
    k_cellB <<<128, 256, 0, stream>>>(ws, dW1, dU1, db1, t);
    k_logits<<<500, 256, 0, stream>>>(ws, out, bout, tgt, tf, t);
  }
}